// Round 1
// baseline (403.917 us; speedup 1.0000x reference)
//
#include <hip/hip_runtime.h>
#include <hip/hip_bf16.h>
#include <stdint.h>

#define K_DIM 4096
#define M_DIM 8192
#define N_DIM 4096

typedef short bf16x8 __attribute__((ext_vector_type(8)));
typedef float f32x4  __attribute__((ext_vector_type(4)));

__device__ __forceinline__ uint16_t f2bf(float f) {
  uint32_t u = __float_as_uint(f);
  u += 0x7fffu + ((u >> 16) & 1u);   // round-to-nearest-even
  return (uint16_t)(u >> 16);
}

__device__ __forceinline__ float wval(float b0, float b1, float b2, float sg) {
  float mg = (b0 >= 0.f ? 0.5f : 0.f) + (b1 >= 0.f ? 0.25f : 0.f) + (b2 >= 0.f ? 0.125f : 0.f);
  return (sg >= 0.f) ? mg : -mg;
}

__device__ __forceinline__ void gload16(const void* g, void* l) {
  typedef __attribute__((address_space(1))) const uint32_t gu32;
  typedef __attribute__((address_space(3))) uint32_t lu32;
  __builtin_amdgcn_global_load_lds((gu32*)g, (lu32*)l, 16, 0, 0);
}

// ---------- Kernel 1: W^T (bf16) build + transpose + per-block sum/sumsq ----
__global__ __launch_bounds__(256) void build_wt(
    const float* __restrict__ mag, const float* __restrict__ sgn,
    uint16_t* __restrict__ wt, float* __restrict__ psum, float* __restrict__ psumsq)
{
  __shared__ float wl[64][65];
  __shared__ float parts[8];
  const int tid = threadIdx.x;
  const int lr = tid >> 4;   // 0..15
  const int lc = tid & 15;   // 0..15
  const int i0 = blockIdx.y * 64;   // input-dim (K) tile
  const int o0 = blockIdx.x * 64;   // output-dim (N) tile
  const float* m0 = mag;
  const float* m1 = mag + (size_t)K_DIM * N_DIM;
  const float* m2 = mag + 2 * (size_t)K_DIM * N_DIM;

  float s = 0.f, s2 = 0.f;
  #pragma unroll
  for (int rg = 0; rg < 4; ++rg) {
    int il = rg * 16 + lr;
    size_t base = (size_t)(i0 + il) * N_DIM + o0 + lc * 4;
    float4 a = *(const float4*)(m0 + base);
    float4 b = *(const float4*)(m1 + base);
    float4 c = *(const float4*)(m2 + base);
    float4 g = *(const float4*)(sgn + base);
    float w0 = wval(a.x, b.x, c.x, g.x);
    float w1 = wval(a.y, b.y, c.y, g.y);
    float w2 = wval(a.z, b.z, c.z, g.z);
    float w3 = wval(a.w, b.w, c.w, g.w);
    wl[il][lc * 4 + 0] = w0;
    wl[il][lc * 4 + 1] = w1;
    wl[il][lc * 4 + 2] = w2;
    wl[il][lc * 4 + 3] = w3;
    s  += w0 + w1 + w2 + w3;
    s2 += w0 * w0 + w1 * w1 + w2 * w2 + w3 * w3;
  }
  // deterministic per-block reduction (no float atomics -> replay-stable)
  #pragma unroll
  for (int off = 32; off > 0; off >>= 1) {
    s  += __shfl_down(s,  off);
    s2 += __shfl_down(s2, off);
  }
  if ((tid & 63) == 0) { parts[tid >> 6] = s; parts[4 + (tid >> 6)] = s2; }
  __syncthreads();
  if (tid == 0) {
    int bid = blockIdx.y * gridDim.x + blockIdx.x;
    psum[bid]   = parts[0] + parts[1] + parts[2] + parts[3];
    psumsq[bid] = parts[4] + parts[5] + parts[6] + parts[7];
  }
  // transposed coalesced write: Wt[o][i]
  #pragma unroll
  for (int rg = 0; rg < 4; ++rg) {
    int ol = rg * 16 + lr;
    int il = lc * 4;
    ushort4 v;
    v.x = f2bf(wl[il + 0][ol]);
    v.y = f2bf(wl[il + 1][ol]);
    v.z = f2bf(wl[il + 2][ol]);
    v.w = f2bf(wl[il + 3][ol]);
    *(ushort4*)(wt + (size_t)(o0 + ol) * K_DIM + i0 + il) = v;
  }
}

// ---------- Kernel 2: x f32 -> bf16 ----------
__global__ __launch_bounds__(256) void cvt_x(const float* __restrict__ x,
                                             uint16_t* __restrict__ xb, int n8)
{
  int idx = blockIdx.x * blockDim.x + threadIdx.x;
  int stride = gridDim.x * blockDim.x;
  for (; idx < n8; idx += stride) {
    float4 v0 = ((const float4*)x)[2 * idx];
    float4 v1 = ((const float4*)x)[2 * idx + 1];
    ushort4 r0, r1;
    r0.x = f2bf(v0.x); r0.y = f2bf(v0.y); r0.z = f2bf(v0.z); r0.w = f2bf(v0.w);
    r1.x = f2bf(v1.x); r1.y = f2bf(v1.y); r1.z = f2bf(v1.z); r1.w = f2bf(v1.w);
    ((ushort4*)xb)[2 * idx]     = r0;
    ((ushort4*)xb)[2 * idx + 1] = r1;
  }
}

// ---------- Kernel 3: alpha = std_target / (std(w) + eps) ----------
__global__ __launch_bounds__(256) void calc_alpha(const float* __restrict__ psum,
                                                  const float* __restrict__ psumsq,
                                                  float* __restrict__ alpha, int nparts)
{
  __shared__ float ls[256], lq[256];
  int tid = threadIdx.x;
  float s = 0.f, q = 0.f;
  for (int i = tid; i < nparts; i += 256) { s += psum[i]; q += psumsq[i]; }
  ls[tid] = s; lq[tid] = q;
  __syncthreads();
  for (int off = 128; off > 0; off >>= 1) {
    if (tid < off) { ls[tid] += ls[tid + off]; lq[tid] += lq[tid + off]; }
    __syncthreads();
  }
  if (tid == 0) {
    const float n = 16777216.f;
    float mean = ls[0] / n;
    float var  = lq[0] / n - mean * mean;
    var = var < 0.f ? 0.f : var;
    float stdv = sqrtf(var);
    alpha[0] = 0.022097086912079608f / (stdv + 1e-8f);  // sqrt(2/4096)/(std+eps)
  }
}

// ---------- Kernel 4: out = alpha * (xb @ Wt^T), bf16 MFMA ----------
// 128x128 tile, BK=64, 4 waves (2x2), each wave 64x64 via 4x4 frags of 16x16x32.
// T2 XOR-swizzle: linear LDS dest for global_load_lds, inverse-swizzled global
// source, swizzled ds_read (involution: cb ^= (row&7)<<4).
__global__ __launch_bounds__(256) void gemm_bf16(
    const uint16_t* __restrict__ xb, const uint16_t* __restrict__ wt,
    const float* __restrict__ alphap, float* __restrict__ out)
{
  __shared__ __align__(16) unsigned char sA[128 * 64 * 2];
  __shared__ __align__(16) unsigned char sB[128 * 64 * 2];
  const int tid  = threadIdx.x;
  const int lane = tid & 63;
  const int wv   = tid >> 6;
  const int wm   = wv >> 1, wn = wv & 1;
  const int bn = blockIdx.x, bm = blockIdx.y;
  const size_t rowA0 = (size_t)bm * 128;
  const size_t rowB0 = (size_t)bn * 128;

  f32x4 acc[4][4] = {};

  // staging lane constants: chunk = 1024B = 8 rows of 128B; lane covers
  // row (c*8 + lane/8), bytes (lane&7)*16. Source column pre-swizzled.
  const int l8      = lane >> 3;                       // row&7 within chunk
  const int src_cb  = ((lane & 7) << 4) ^ (l8 << 4);   // inverse-swizzled col byte
  const int frag_cb = ((lane >> 4) << 4);              // fragment k-col byte base
  const int swz     = (lane & 7) << 4;                 // read-side swizzle (row&7 = lane&7)

  for (int k0 = 0; k0 < K_DIM; k0 += 64) {
    #pragma unroll
    for (int it = 0; it < 4; ++it) {
      int c = wv * 4 + it;
      int row = c * 8 + l8;
      const char* gA = (const char*)xb + (((rowA0 + row) * K_DIM + k0) << 1) + src_cb;
      const char* gB = (const char*)wt + (((rowB0 + row) * K_DIM + k0) << 1) + src_cb;
      gload16(gA, sA + c * 1024);
      gload16(gB, sB + c * 1024);
    }
    __syncthreads();

    #pragma unroll
    for (int kk = 0; kk < 2; ++kk) {
      bf16x8 af[4], bfr[4];
      #pragma unroll
      for (int m = 0; m < 4; ++m) {
        int row = wm * 64 + m * 16 + (lane & 15);
        int cb  = (kk * 64 + frag_cb) ^ swz;
        af[m] = *(const bf16x8*)(sA + row * 128 + cb);
      }
      #pragma unroll
      for (int n = 0; n < 4; ++n) {
        int row = wn * 64 + n * 16 + (lane & 15);
        int cb  = (kk * 64 + frag_cb) ^ swz;
        bfr[n] = *(const bf16x8*)(sB + row * 128 + cb);
      }
      #pragma unroll
      for (int m = 0; m < 4; ++m)
        #pragma unroll
        for (int n = 0; n < 4; ++n)
          acc[m][n] = __builtin_amdgcn_mfma_f32_16x16x32_bf16(af[m], bfr[n], acc[m][n], 0, 0, 0);
    }
    __syncthreads();
  }

  const float alpha = alphap[0];
  const int ccol  = bn * 128 + wn * 64 + (lane & 15);
  const int crow0 = bm * 128 + wm * 64 + ((lane >> 4) << 2);
  #pragma unroll
  for (int m = 0; m < 4; ++m)
    #pragma unroll
    for (int n = 0; n < 4; ++n)
      #pragma unroll
      for (int r = 0; r < 4; ++r)
        out[(size_t)(crow0 + m * 16 + r) * N_DIM + ccol + n * 16] = acc[m][n][r] * alpha;
}

extern "C" void kernel_launch(void* const* d_in, const int* in_sizes, int n_in,
                              void* d_out, int out_size, void* d_ws, size_t ws_size,
                              hipStream_t stream) {
  const float* x   = (const float*)d_in[0];
  const float* mag = (const float*)d_in[1];
  const float* sgn = (const float*)d_in[2];
  float* out = (float*)d_out;

  char* ws = (char*)d_ws;
  float* alpha    = (float*)ws;
  float* psum     = (float*)(ws + 256);
  float* psumsq   = (float*)(ws + 256 + 16384);
  uint16_t* wt    = (uint16_t*)(ws + 256 + 32768);
  uint16_t* xb    = (uint16_t*)(ws + 256 + 32768 + 33554432ull);
  size_t needed = 256 + 32768 + 33554432ull + 67108864ull;
  if (ws_size < needed) return;  // would corrupt otherwise; bench will show stub-like absmax

  build_wt<<<dim3(64, 64), 256, 0, stream>>>(mag, sgn, wt, psum, psumsq);
  cvt_x<<<dim3(2048), 256, 0, stream>>>(x, xb, (M_DIM * K_DIM) / 8);
  calc_alpha<<<dim3(1), 256, 0, stream>>>(psum, psumsq, alpha, 4096);
  gemm_bf16<<<dim3(N_DIM / 128, M_DIM / 128), 256, 0, stream>>>(xb, wt, alpha, out);
}